// Round 12
// baseline (783.361 us; speedup 1.0000x reference)
//
#include <hip/hip_runtime.h>
#include <hip/hip_fp16.h>

// ---------------------------------------------------------------------------
// MLPForwardPolicy — r11 skeleton, W streamed ONCE (BM=256 x BN=128, 8-wave).
//
// Staged-bytes ledger (G1): r7/r11 both ~1.78 GB DMA'd; this round:
// W 604 MB (once) + A 0.6 GB = 1.21 GB (-32%); G2/3: 1.02 -> 0.64 GB.
//   * 512-thr blocks, 8 waves 4x2: wave(wm,wn) = 64 rows x 64 cols, acc[4][4]
//     (r3's proven ~84-110 VGPR shape); launch_bounds(512,2) -> cap 128,
//     16 waves/CU = 4/SIMD for cross-wave wait/compute overlap.
//   * W: global_load_lds 16 KB/stage, ring 2 = 32 KB, XOR granule swizzle
//     p = cg ^ 5q (2-way = free), 2 instr/thread/stage.
//   * A: direct global->VGPR rings aE/aO, TWO-PHASE unrolled loop (static reg
//     indexing, rule 20), 4 instr/thread/stage.
//   * vmcnt(6) steady / vmcnt(0) tail; 2 raw barriers/step; rule-18 fences.
// Ranking: r11=592 r7=606 r10=656 r3=663 r6=669 r8=686 r9=694.
// ---------------------------------------------------------------------------

typedef _Float16 f16;
typedef _Float16 f16x4 __attribute__((ext_vector_type(4)));
typedef _Float16 f16x8 __attribute__((ext_vector_type(8)));
typedef float f32x4 __attribute__((ext_vector_type(4)));

#define DH 9216
#define SPLIT 8960

__device__ __forceinline__ void gload16(const void* g, void* l) {
    __builtin_amdgcn_global_load_lds(
        (const __attribute__((address_space(1))) void*)g,
        (__attribute__((address_space(3))) void*)l, 16, 0, 0);
}

// ---------------- f32 -> f16 ----------------
__global__ void cvt_kernel(const float* __restrict__ in, f16* __restrict__ out, int n) {
    for (int i = (blockIdx.x * blockDim.x + threadIdx.x) * 4; i < n;
         i += gridDim.x * blockDim.x * 4) {
        float4 v = *(const float4*)(in + i);
        f16x4 h = {(_Float16)v.x, (_Float16)v.y, (_Float16)v.z, (_Float16)v.w};
        *(f16x4*)(out + i) = h;
    }
}

// ---------------- streaming GEMM: P[y] = A[256,Kh] @ W[Kh, 128-col slice] ---
// linear grid 72<<yshift blocks of 512 threads; y = bid & (S-1)
// 8 waves 4x2: wave(wm = wid>>1, wn = wid&1) owns rows wm*64..+64 x
// cols n0 + wn*64..+64
__global__ __launch_bounds__(512, 2) void gemm_kernel(
    const f16* __restrict__ A, int K, int Kh, int yshift,
    const float* __restrict__ W,
    float* __restrict__ P)   // [S][256][9216]
{
    __shared__ __align__(16) char lds[2][16384];   // W f32 [32k][128c swz], x2
    const int bid  = blockIdx.x;
    const int y    = bid & ((1 << yshift) - 1);
    const int n0   = (bid >> yshift) << 7;
    const int tid  = threadIdx.x;
    const int lane = tid & 63;
    const int wid  = tid >> 6;
    const int wm   = wid >> 1, wn = wid & 1;
    const int kbase = y * Kh;
    const int ns   = Kh >> 5;                      // BK=32; 64 or 36 (even)

    f32x4 acc[4][4] = {};
    f16x8 aE[4], aO[4];

    // ---- hoisted W DMA source pointers (2 granules/thread/stage) ----
    // granule g (0..1023): k = g>>5, p = g&31, src col-group cg = p ^ (5*(k>>3)&31)
    const float* wsrc0;
    const float* wsrc1;
    {
        int g0 = tid,       k0 = g0 >> 5, c0 = (g0 & 31) ^ ((5 * (k0 >> 3)) & 31);
        int g1 = tid + 512, k1 = g1 >> 5, c1 = (g1 & 31) ^ ((5 * (k1 >> 3)) & 31);
        wsrc0 = W + (size_t)(kbase + k0) * DH + n0 + (c0 << 2);
        wsrc1 = W + (size_t)(kbase + k1) * DH + n0 + (c1 << 2);
    }
    const int q  = lane >> 4;          // 0..3
    const int lc = lane & 15;
    const f16* abase = A + (size_t)(wm * 64 + lc) * K + kbase + (q << 3);

    auto issueW = [&](int slot) {      // advances pointers one stage
        char* dst = &lds[slot][0];
        gload16(wsrc0, dst + (size_t)tid * 16);         wsrc0 += 32 * DH;
        gload16(wsrc1, dst + (size_t)(tid + 512) * 16); wsrc1 += 32 * DH;
    };
    auto loadA = [&](f16x8* a, int t) {   // 4 x 16B direct to VGPR
        const f16* p = abase + (t << 5);
#pragma unroll
        for (int ri = 0; ri < 4; ++ri)
            a[ri] = *(const f16x8*)(p + (size_t)(ri << 4) * K);
    };
    auto mfma_step = [&](int slot, f16x8* a) {
        const float* wl = (const float*)&lds[slot][0];
        const int wbase = (q << 10) + (lc & 3);        // k = q*8 rows of 128 f32
        f16x8 bf[4];
#pragma unroll
        for (int ni = 0; ni < 4; ++ni) {
            int p = ((wn << 4) + (ni << 2) + (lc >> 2)) ^ (5 * q);
            int fi = wbase + ((p & 31) << 2);
            f16x8 b;
#pragma unroll
            for (int j = 0; j < 8; ++j)
                b[j] = (_Float16)wl[fi + (j << 7)];
            bf[ni] = b;
        }
#pragma unroll
        for (int ri = 0; ri < 4; ++ri)
#pragma unroll
            for (int ni = 0; ni < 4; ++ni)
                acc[ri][ni] = __builtin_amdgcn_mfma_f32_16x16x32_f16(
                    a[ri], bf[ni], acc[ri][ni], 0, 0, 0);
    };

    // prologue: stages 0 and 1 in flight (6 VMEM instr/thread each)
    issueW(0); loadA(aE, 0);
    issueW(1); loadA(aO, 1);
    __builtin_amdgcn_sched_barrier(0);

    for (int t = 0; t < ns; t += 2) {
        // ---- phase A: step t (slot 0, aE) ----
        asm volatile("s_waitcnt vmcnt(6)" ::: "memory");  // stage t done
        __builtin_amdgcn_sched_barrier(0);
        __builtin_amdgcn_s_barrier();
        __builtin_amdgcn_sched_barrier(0);
        mfma_step(0, aE);
        __builtin_amdgcn_sched_barrier(0);
        asm volatile("s_waitcnt lgkmcnt(0)" ::: "memory");
        __builtin_amdgcn_sched_barrier(0);
        __builtin_amdgcn_s_barrier();
        __builtin_amdgcn_sched_barrier(0);
        if (t + 2 < ns) {
            issueW(0); loadA(aE, t + 2);
            __builtin_amdgcn_sched_barrier(0);
        }
        // ---- phase B: step t+1 (slot 1, aO) ----
        if (t + 2 < ns) asm volatile("s_waitcnt vmcnt(6)" ::: "memory");
        else            asm volatile("s_waitcnt vmcnt(0)" ::: "memory");
        __builtin_amdgcn_sched_barrier(0);
        __builtin_amdgcn_s_barrier();
        __builtin_amdgcn_sched_barrier(0);
        mfma_step(1, aO);
        __builtin_amdgcn_sched_barrier(0);
        asm volatile("s_waitcnt lgkmcnt(0)" ::: "memory");
        __builtin_amdgcn_sched_barrier(0);
        __builtin_amdgcn_s_barrier();
        __builtin_amdgcn_sched_barrier(0);
        if (t + 3 < ns) {
            issueW(1); loadA(aO, t + 3);
            __builtin_amdgcn_sched_barrier(0);
        }
    }

    // epilogue: D layout col=lane&15, row=(lane>>4)*4+reg  [m89-verified]
    float* Pb = P + (size_t)y * (256 * DH);
#pragma unroll
    for (int ri = 0; ri < 4; ++ri) {
        int row = wm * 64 + ri * 16 + (q << 2);
#pragma unroll
        for (int ni = 0; ni < 4; ++ni) {
            int col = n0 + wn * 64 + ni * 16 + lc;
#pragma unroll
            for (int rg = 0; rg < 4; ++rg)
                Pb[(size_t)(row + rg) * DH + col] = acc[ri][ni][rg];
        }
    }
}

// ---------------- splitK reduce + bias + relu -> f16 and/or f32 -------------
__global__ void reduce_kernel(const float* __restrict__ P, int S,
                              const float* __restrict__ bias,
                              f16* __restrict__ oh, float* __restrict__ out32) {
    const int n = 256 * DH;
    for (int i = (blockIdx.x * blockDim.x + threadIdx.x) * 4; i < n;
         i += gridDim.x * blockDim.x * 4) {
        float4 bb = *(const float4*)(bias + (i % DH));
        float4 r = bb;
        for (int j = 0; j < S; ++j) {
            float4 a = *(const float4*)(P + (size_t)j * n + i);
            r.x += a.x; r.y += a.y; r.z += a.z; r.w += a.w;
        }
        r.x = fmaxf(r.x, 0.f); r.y = fmaxf(r.y, 0.f);
        r.z = fmaxf(r.z, 0.f); r.w = fmaxf(r.w, 0.f);
        if (oh) {
            f16x4 h = {(_Float16)r.x, (_Float16)r.y, (_Float16)r.z, (_Float16)r.w};
            *(f16x4*)(oh + i) = h;
        }
        if (out32) *(float4*)(out32 + i) = r;
    }
}

// ---------------- action head: softmax(X3[:, :8960] @ Wa + ba) --------------
__global__ __launch_bounds__(256) void action_kernel(
    const float* __restrict__ X3, const float* __restrict__ Wa,
    const float* __restrict__ ba, float* __restrict__ xact) {
    __shared__ float xs[SPLIT];
    __shared__ float red[256];
    const int row = blockIdx.x, t = threadIdx.x;
    const float* xr = X3 + (size_t)row * DH;
    for (int k = t * 4; k < SPLIT; k += 1024)
        *(float4*)&xs[k] = *(const float4*)(xr + k);
    __syncthreads();
    const int col = t & 63, kqq = t >> 6;
    float acc = 0.f;
    for (int k = kqq * 2240; k < (kqq + 1) * 2240; ++k)
        acc += xs[k] * Wa[(size_t)k * 64 + col];
    red[t] = acc;
    __syncthreads();
    if (t < 64) {
        float z = red[t] + red[t + 64] + red[t + 128] + red[t + 192] + ba[t];
        float mx = z;
        for (int off = 32; off; off >>= 1) mx = fmaxf(mx, __shfl_xor(mx, off));
        float e = expf(z - mx);
        float s = e;
        for (int off = 32; off; off >>= 1) s += __shfl_xor(s, off);
        xact[row * 64 + t] = e / s;
    }
}

// ---------------- selection head + final outputs ---------------------------
__global__ __launch_bounds__(256) void select_kernel(
    const float* __restrict__ X3, const float* __restrict__ Ws,
    const float* __restrict__ bs, const void* __restrict__ maskp,
    const float* __restrict__ u, const float* __restrict__ xact,
    float* __restrict__ out) {
    __shared__ float xs[256];
    __shared__ float psh[256];
    __shared__ float rr[4];
    __shared__ float bestv[4];
    __shared__ int besti[4];
    __shared__ int sIdx;
    __shared__ int smode;
    const int row = blockIdx.x, t = threadIdx.x;
    const int lane = t & 63, wid = t >> 6;

    // mask dtype detection: int32 {0,1} / bytes {0,1} / float {0.f,1.f}
    if (t < 64) {
        unsigned v = ((const unsigned*)maskp)[t];
        int okInt  = __all(v <= 1u);
        int okByte = __all((v & 0xFEFEFEFEu) == 0u);
        if (t == 0) smode = okInt ? 0 : (okByte ? 1 : 2);
    }
    xs[t] = X3[(size_t)row * DH + SPLIT + t];
    __syncthreads();

    bool mk;
    if (smode == 0)       mk = ((const int*)maskp)[row * 256 + t] != 0;
    else if (smode == 1)  mk = ((const unsigned char*)maskp)[row * 256 + t] != 0;
    else                  mk = ((const float*)maskp)[row * 256 + t] != 0.0f;

    float z = bs[t];
    for (int k = 0; k < 256; ++k)
        z += xs[k] * Ws[k * 256 + t];

    // softmax #1
    float v = z;
    for (int off = 32; off; off >>= 1) v = fmaxf(v, __shfl_xor(v, off));
    if (lane == 0) rr[wid] = v;
    __syncthreads();
    float m1 = fmaxf(fmaxf(rr[0], rr[1]), fmaxf(rr[2], rr[3]));
    __syncthreads();
    float e1 = expf(z - m1);
    v = e1;
    for (int off = 32; off; off >>= 1) v += __shfl_xor(v, off);
    if (lane == 0) rr[wid] = v;
    __syncthreads();
    float s1 = rr[0] + rr[1] + rr[2] + rr[3];
    __syncthreads();
    float p1 = e1 / s1;

    // mask, softmax #2
    float q = mk ? -1e9f : p1;
    v = q;
    for (int off = 32; off; off >>= 1) v = fmaxf(v, __shfl_xor(v, off));
    if (lane == 0) rr[wid] = v;
    __syncthreads();
    float m2 = fmaxf(fmaxf(rr[0], rr[1]), fmaxf(rr[2], rr[3]));
    __syncthreads();
    float e2 = expf(q - m2);
    v = e2;
    for (int off = 32; off; off >>= 1) v += __shfl_xor(v, off);
    if (lane == 0) rr[wid] = v;
    __syncthreads();
    float s2 = rr[0] + rr[1] + rr[2] + rr[3];
    float p2 = e2 / s2;
    psh[t] = p2;

    // gumbel scores + first-occurrence argmax
    float g = -logf(-logf(u[row * 256 + t]));
    float sc = mk ? -INFINITY : (logf(p2) + g);
    float bv = sc;
    int bi = t;
    for (int off = 32; off; off >>= 1) {
        float ov = __shfl_xor(bv, off);
        int oi = __shfl_xor(bi, off);
        if (ov > bv || (ov == bv && oi < bi)) { bv = ov; bi = oi; }
    }
    if (lane == 0) { bestv[wid] = bv; besti[wid] = bi; }
    __syncthreads();
    if (t == 0) {
        float fv = bestv[0];
        int fi = besti[0];
        for (int w = 1; w < 4; ++w)
            if (bestv[w] > fv || (bestv[w] == fv && besti[w] < fi)) {
                fv = bestv[w]; fi = besti[w];
            }
        sIdx = fi;
    }
    __syncthreads();
    const int idx = sIdx;
    const float sp = psh[idx];
    if (t < 64) out[row * 64 + t] = xact[row * 64 + t] * sp;
    if (t == 0) {
        out[256 * 64 + row * 2 + 0] = (float)(idx >> 4);
        out[256 * 64 + row * 2 + 1] = (float)(idx & 15);
    }
}

// ---------------------------------------------------------------------------
extern "C" void kernel_launch(void* const* d_in, const int* in_sizes, int n_in,
                              void* d_out, int out_size, void* d_ws, size_t ws_size,
                              hipStream_t stream) {
    const float* s  = (const float*)d_in[0];
    const void*  mask = d_in[1];
    const float* u  = (const float*)d_in[2];
    const float* W1 = (const float*)d_in[3];
    const float* b1 = (const float*)d_in[4];
    const float* W2 = (const float*)d_in[5];
    const float* b2 = (const float*)d_in[6];
    const float* W3 = (const float*)d_in[7];
    const float* b3 = (const float*)d_in[8];
    const float* Wa = (const float*)d_in[9];
    const float* ba = (const float*)d_in[10];
    const float* Ws = (const float*)d_in[11];
    const float* bs = (const float*)d_in[12];
    float* out = (float*)d_out;
    char* ws = (char*)d_ws;

    // workspace map:
    //   [0,        8,388,608)  A0 f16 [256][16384]   (reused by X2 after gemm1)
    //   [8388608, 13,107,200)  X1 f16 [256][9216]
    //   [13107200,22,544,384)  X3 f32 [256][9216]
    //   [22544384,22,609,920)  XA f32 [256][64]
    //   [22609920, ...)        P  f32 [S][256][9216]
    f16*   A0 = (f16*)(ws + 0);
    f16*   X1 = (f16*)(ws + 8388608);
    f16*   X2 = (f16*)(ws + 0);            // reuses dead A0
    float* X3 = (float*)(ws + 13107200);
    float* XA = (float*)(ws + 22544384);
    float* P  = (float*)(ws + 22609920);

    const size_t pbytes = 9437184ull;      // one splitK plane
    int yshift = (ws_size >= 22609920ull + 8 * pbytes) ? 3 : 2;
    const int S = 1 << yshift;

    cvt_kernel<<<2048, 256, 0, stream>>>(s, A0, 256 * 16384);

    const int nblk = 72 << yshift;         // 576 @ S=8; y = bid & (S-1)
    gemm_kernel<<<nblk, 512, 0, stream>>>(A0, 16384, 16384 / S, yshift, W1, P);
    reduce_kernel<<<1152, 256, 0, stream>>>(P, S, b1, X1, nullptr);
    gemm_kernel<<<nblk, 512, 0, stream>>>(X1, DH, DH / S, yshift, W2, P);
    reduce_kernel<<<1152, 256, 0, stream>>>(P, S, b2, X2, nullptr);
    gemm_kernel<<<nblk, 512, 0, stream>>>(X2, DH, DH / S, yshift, W3, P);
    reduce_kernel<<<1152, 256, 0, stream>>>(P, S, b3, nullptr, X3);

    action_kernel<<<256, 256, 0, stream>>>(X3, Wa, ba, XA);
    select_kernel<<<256, 256, 0, stream>>>(X3, Ws, bs, mask, u, XA, out);
}

// Round 15
// 656.285 us; speedup vs baseline: 1.1936x; 1.1936x over previous
//
#include <hip/hip_runtime.h>
#include <hip/hip_fp16.h>

// ---------------------------------------------------------------------------
// MLPForwardPolicy — r11 winning kernel VERBATIM (BM=128 x BN=128 m-pair,
// all-DMA, XOR-swizzled W, counted vmcnt(6), 2 barriers/step), with ONE
// change: splitK S=8 -> S=4 (yshift 2, nblk 576).
// Rationale: r14 (BN=96, S=4) failed coords by 8.0 with no findable geometry
// bug; X3 numerics depend only on S, so this run separates (a) BN=96 geometry
// bug [r15 passes] from (b) S=4 split-rounding argmax tie-flip [r15 fails].
// Side benefit: P traffic halves (75->37.7 MB/layer) and 576 blocks are
// fully resident (no 2nd dispatch round).
// Ranking: r11=592 r7=606 r10=656 r3=663 r6=669 r8=686 r9=694 r12=783.
// ---------------------------------------------------------------------------

typedef _Float16 f16;
typedef _Float16 f16x4 __attribute__((ext_vector_type(4)));
typedef _Float16 f16x8 __attribute__((ext_vector_type(8)));
typedef float f32x4 __attribute__((ext_vector_type(4)));

#define DH 9216
#define SPLIT 8960

__device__ __forceinline__ void gload16(const void* g, void* l) {
    __builtin_amdgcn_global_load_lds(
        (const __attribute__((address_space(1))) void*)g,
        (__attribute__((address_space(3))) void*)l, 16, 0, 0);
}

// ---------------- f32 -> f16 ----------------
__global__ void cvt_kernel(const float* __restrict__ in, f16* __restrict__ out, int n) {
    for (int i = (blockIdx.x * blockDim.x + threadIdx.x) * 4; i < n;
         i += gridDim.x * blockDim.x * 4) {
        float4 v = *(const float4*)(in + i);
        f16x4 h = {(_Float16)v.x, (_Float16)v.y, (_Float16)v.z, (_Float16)v.w};
        *(f16x4*)(out + i) = h;
    }
}

// ---------------- streaming GEMM: P[y] = A[128-row][Kh] @ W[Kh, 128-col] ----
// linear grid (2*72)<<yshift blocks of 256 threads; y = bid & (S-1)
// rem = bid >> yshift: m0 = (rem&1)*128, n0 = (rem>>1)*128
// 4 waves 2x2: wave(wm,wn) owns rows m0+wm*64..+64 x cols n0+wn*64..+64
__global__ __launch_bounds__(256, 3) void gemm_kernel(
    const f16* __restrict__ A, int K, int Kh, int yshift,
    const float* __restrict__ W,
    float* __restrict__ P)   // [S][256][9216]
{
    __shared__ __align__(16) char lds[2][24576];
    const int bid  = blockIdx.x;
    const int y    = bid & ((1 << yshift) - 1);
    const int rem  = bid >> yshift;
    const int m0   = (rem & 1) << 7;
    const int n0   = (rem >> 1) << 7;
    const int tid  = threadIdx.x;
    const int lane = tid & 63;
    const int wid  = tid >> 6;
    const int wm   = wid >> 1, wn = wid & 1;
    const int kbase = y * Kh;
    const int ns   = Kh >> 5;                     // BK = 32

    f32x4 acc[4][4] = {};

    // ---- hoisted DMA source pointers (advance by one stage per issue) ----
    // W: granule g = tid + r*256 (1024 total): k = g>>5, p = g&31,
    //    src col-group cg = p ^ ((5*(k>>3)) & 31)
    const float* wsrc0;
    const float* wsrc1;
    const float* wsrc2;
    const float* wsrc3;
    {
        int g0 = tid,      k0 = g0 >> 5, c0 = (g0 & 31) ^ ((5 * (k0 >> 3)) & 31);
        int g1 = tid + 256, k1 = g1 >> 5, c1 = (g1 & 31) ^ ((5 * (k1 >> 3)) & 31);
        int g2 = tid + 512, k2 = g2 >> 5, c2 = (g2 & 31) ^ ((5 * (k2 >> 3)) & 31);
        int g3 = tid + 768, k3 = g3 >> 5, c3 = (g3 & 31) ^ ((5 * (k3 >> 3)) & 31);
        wsrc0 = W + (size_t)(kbase + k0) * DH + n0 + (c0 << 2);
        wsrc1 = W + (size_t)(kbase + k1) * DH + n0 + (c1 << 2);
        wsrc2 = W + (size_t)(kbase + k2) * DH + n0 + (c2 << 2);
        wsrc3 = W + (size_t)(kbase + k3) * DH + n0 + (c3 << 2);
    }
    // A: granule h = tid + r*256 (512 total): wmA = h>>8, ri = (h>>6)&3,
    //    q = (h>>4)&3, lc = h&15 -> A[m0 + wmA*64 + ri*16 + lc][kt + q*8..+8]
    const f16* asrc0;
    const f16* asrc1;
    {
        int h0 = tid, h1 = tid + 256;
        int r0 = m0 + ((h0 >> 8) << 6) + (((h0 >> 6) & 3) << 4) + (h0 & 15);
        int r1 = m0 + ((h1 >> 8) << 6) + (((h1 >> 6) & 3) << 4) + (h1 & 15);
        asrc0 = A + (size_t)r0 * K + kbase + (((h0 >> 4) & 3) << 3);
        asrc1 = A + (size_t)r1 * K + kbase + (((h1 >> 4) & 3) << 3);
    }

    auto issue = [&](int slot) {      // 6 DMA instr/thread; advance ptrs 1 stage
        char* dst = &lds[slot][0];
        gload16(wsrc0, dst + (size_t)tid * 16);          wsrc0 += 32 * DH;
        gload16(wsrc1, dst + (size_t)(tid + 256) * 16);  wsrc1 += 32 * DH;
        gload16(wsrc2, dst + (size_t)(tid + 512) * 16);  wsrc2 += 32 * DH;
        gload16(wsrc3, dst + (size_t)(tid + 768) * 16);  wsrc3 += 32 * DH;
        gload16(asrc0, dst + 16384 + (size_t)tid * 16);         asrc0 += 32;
        gload16(asrc1, dst + 16384 + (size_t)(tid + 256) * 16); asrc1 += 32;
    };

    const int q  = lane >> 4;
    const int lc = lane & 15;
    auto step = [&](int slot) {
        const float* wl = (const float*)&lds[slot][0];
        const f16*   al = (const f16*)&lds[slot][16384];
        f16x8 af[4], bf[4];
#pragma unroll
        for (int ri = 0; ri < 4; ++ri)      // lane-linear b128: conflict-free
            af[ri] = *(const f16x8*)(al + (((wm << 8) + (ri << 6) + lane) << 3));
        const int wbase = (q << 10) + (lc & 3);           // k = q*8 -> q*8*128
#pragma unroll
        for (int ni = 0; ni < 4; ++ni) {
            int p = ((wn << 4) + (ni << 2) + (lc >> 2)) ^ (5 * q);
            int fi = wbase + ((p & 31) << 2);
            f16x8 b;
#pragma unroll
            for (int j = 0; j < 8; ++j)
                b[j] = (_Float16)wl[fi + (j << 7)];
            bf[ni] = b;
        }
#pragma unroll
        for (int ri = 0; ri < 4; ++ri)
#pragma unroll
            for (int ni = 0; ni < 4; ++ni)
                acc[ri][ni] = __builtin_amdgcn_mfma_f32_16x16x32_f16(
                    af[ri], bf[ni], acc[ri][ni], 0, 0, 0);
    };

    issue(0);
    issue(1);
    __builtin_amdgcn_sched_barrier(0);

    for (int t = 0; t < ns; ++t) {
        if (t + 1 < ns) asm volatile("s_waitcnt vmcnt(6)" ::: "memory");
        else            asm volatile("s_waitcnt vmcnt(0)" ::: "memory");
        __builtin_amdgcn_sched_barrier(0);
        __builtin_amdgcn_s_barrier();
        __builtin_amdgcn_sched_barrier(0);
        step(t & 1);
        __builtin_amdgcn_sched_barrier(0);
        asm volatile("s_waitcnt lgkmcnt(0)" ::: "memory");
        __builtin_amdgcn_sched_barrier(0);
        __builtin_amdgcn_s_barrier();
        __builtin_amdgcn_sched_barrier(0);
        if (t + 2 < ns) {
            issue(t & 1);
            __builtin_amdgcn_sched_barrier(0);
        }
    }

    // epilogue: D layout col=lane&15, row=(lane>>4)*4+reg  [m89-verified]
    float* Pb = P + (size_t)y * (256 * DH);
#pragma unroll
    for (int ri = 0; ri < 4; ++ri) {
        int row = m0 + wm * 64 + ri * 16 + (q << 2);
#pragma unroll
        for (int ni = 0; ni < 4; ++ni) {
            int col = n0 + wn * 64 + ni * 16 + lc;
#pragma unroll
            for (int rg = 0; rg < 4; ++rg)
                Pb[(size_t)(row + rg) * DH + col] = acc[ri][ni][rg];
        }
    }
}

// ---------------- splitK reduce + bias + relu -> f16 and/or f32 -------------
__global__ void reduce_kernel(const float* __restrict__ P, int S,
                              const float* __restrict__ bias,
                              f16* __restrict__ oh, float* __restrict__ out32) {
    const int n = 256 * DH;
    for (int i = (blockIdx.x * blockDim.x + threadIdx.x) * 4; i < n;
         i += gridDim.x * blockDim.x * 4) {
        float4 bb = *(const float4*)(bias + (i % DH));
        float4 r = bb;
        for (int j = 0; j < S; ++j) {
            float4 a = *(const float4*)(P + (size_t)j * n + i);
            r.x += a.x; r.y += a.y; r.z += a.z; r.w += a.w;
        }
        r.x = fmaxf(r.x, 0.f); r.y = fmaxf(r.y, 0.f);
        r.z = fmaxf(r.z, 0.f); r.w = fmaxf(r.w, 0.f);
        if (oh) {
            f16x4 h = {(_Float16)r.x, (_Float16)r.y, (_Float16)r.z, (_Float16)r.w};
            *(f16x4*)(oh + i) = h;
        }
        if (out32) *(float4*)(out32 + i) = r;
    }
}

// ---------------- action head: softmax(X3[:, :8960] @ Wa + ba) --------------
__global__ __launch_bounds__(256) void action_kernel(
    const float* __restrict__ X3, const float* __restrict__ Wa,
    const float* __restrict__ ba, float* __restrict__ xact) {
    __shared__ float xs[SPLIT];
    __shared__ float red[256];
    const int row = blockIdx.x, t = threadIdx.x;
    const float* xr = X3 + (size_t)row * DH;
    for (int k = t * 4; k < SPLIT; k += 1024)
        *(float4*)&xs[k] = *(const float4*)(xr + k);
    __syncthreads();
    const int col = t & 63, kqq = t >> 6;
    float acc = 0.f;
    for (int k = kqq * 2240; k < (kqq + 1) * 2240; ++k)
        acc += xs[k] * Wa[(size_t)k * 64 + col];
    red[t] = acc;
    __syncthreads();
    if (t < 64) {
        float z = red[t] + red[t + 64] + red[t + 128] + red[t + 192] + ba[t];
        float mx = z;
        for (int off = 32; off; off >>= 1) mx = fmaxf(mx, __shfl_xor(mx, off));
        float e = expf(z - mx);
        float s = e;
        for (int off = 32; off; off >>= 1) s += __shfl_xor(s, off);
        xact[row * 64 + t] = e / s;
    }
}

// ---------------- selection head + final outputs ---------------------------
__global__ __launch_bounds__(256) void select_kernel(
    const float* __restrict__ X3, const float* __restrict__ Ws,
    const float* __restrict__ bs, const void* __restrict__ maskp,
    const float* __restrict__ u, const float* __restrict__ xact,
    float* __restrict__ out) {
    __shared__ float xs[256];
    __shared__ float psh[256];
    __shared__ float rr[4];
    __shared__ float bestv[4];
    __shared__ int besti[4];
    __shared__ int sIdx;
    __shared__ int smode;
    const int row = blockIdx.x, t = threadIdx.x;
    const int lane = t & 63, wid = t >> 6;

    // mask dtype detection: int32 {0,1} / bytes {0,1} / float {0.f,1.f}
    if (t < 64) {
        unsigned v = ((const unsigned*)maskp)[t];
        int okInt  = __all(v <= 1u);
        int okByte = __all((v & 0xFEFEFEFEu) == 0u);
        if (t == 0) smode = okInt ? 0 : (okByte ? 1 : 2);
    }
    xs[t] = X3[(size_t)row * DH + SPLIT + t];
    __syncthreads();

    bool mk;
    if (smode == 0)       mk = ((const int*)maskp)[row * 256 + t] != 0;
    else if (smode == 1)  mk = ((const unsigned char*)maskp)[row * 256 + t] != 0;
    else                  mk = ((const float*)maskp)[row * 256 + t] != 0.0f;

    float z = bs[t];
    for (int k = 0; k < 256; ++k)
        z += xs[k] * Ws[k * 256 + t];

    // softmax #1
    float v = z;
    for (int off = 32; off; off >>= 1) v = fmaxf(v, __shfl_xor(v, off));
    if (lane == 0) rr[wid] = v;
    __syncthreads();
    float m1 = fmaxf(fmaxf(rr[0], rr[1]), fmaxf(rr[2], rr[3]));
    __syncthreads();
    float e1 = expf(z - m1);
    v = e1;
    for (int off = 32; off; off >>= 1) v += __shfl_xor(v, off);
    if (lane == 0) rr[wid] = v;
    __syncthreads();
    float s1 = rr[0] + rr[1] + rr[2] + rr[3];
    __syncthreads();
    float p1 = e1 / s1;

    // mask, softmax #2
    float q = mk ? -1e9f : p1;
    v = q;
    for (int off = 32; off; off >>= 1) v = fmaxf(v, __shfl_xor(v, off));
    if (lane == 0) rr[wid] = v;
    __syncthreads();
    float m2 = fmaxf(fmaxf(rr[0], rr[1]), fmaxf(rr[2], rr[3]));
    __syncthreads();
    float e2 = expf(q - m2);
    v = e2;
    for (int off = 32; off; off >>= 1) v += __shfl_xor(v, off);
    if (lane == 0) rr[wid] = v;
    __syncthreads();
    float s2 = rr[0] + rr[1] + rr[2] + rr[3];
    float p2 = e2 / s2;
    psh[t] = p2;

    // gumbel scores + first-occurrence argmax
    float g = -logf(-logf(u[row * 256 + t]));
    float sc = mk ? -INFINITY : (logf(p2) + g);
    float bv = sc;
    int bi = t;
    for (int off = 32; off; off >>= 1) {
        float ov = __shfl_xor(bv, off);
        int oi = __shfl_xor(bi, off);
        if (ov > bv || (ov == bv && oi < bi)) { bv = ov; bi = oi; }
    }
    if (lane == 0) { bestv[wid] = bv; besti[wid] = bi; }
    __syncthreads();
    if (t == 0) {
        float fv = bestv[0];
        int fi = besti[0];
        for (int w = 1; w < 4; ++w)
            if (bestv[w] > fv || (bestv[w] == fv && besti[w] < fi)) {
                fv = bestv[w]; fi = besti[w];
            }
        sIdx = fi;
    }
    __syncthreads();
    const int idx = sIdx;
    const float sp = psh[idx];
    if (t < 64) out[row * 64 + t] = xact[row * 64 + t] * sp;
    if (t == 0) {
        out[256 * 64 + row * 2 + 0] = (float)(idx >> 4);
        out[256 * 64 + row * 2 + 1] = (float)(idx & 15);
    }
}

// ---------------------------------------------------------------------------
extern "C" void kernel_launch(void* const* d_in, const int* in_sizes, int n_in,
                              void* d_out, int out_size, void* d_ws, size_t ws_size,
                              hipStream_t stream) {
    const float* s  = (const float*)d_in[0];
    const void*  mask = d_in[1];
    const float* u  = (const float*)d_in[2];
    const float* W1 = (const float*)d_in[3];
    const float* b1 = (const float*)d_in[4];
    const float* W2 = (const float*)d_in[5];
    const float* b2 = (const float*)d_in[6];
    const float* W3 = (const float*)d_in[7];
    const float* b3 = (const float*)d_in[8];
    const float* Wa = (const float*)d_in[9];
    const float* ba = (const float*)d_in[10];
    const float* Ws = (const float*)d_in[11];
    const float* bs = (const float*)d_in[12];
    float* out = (float*)d_out;
    char* ws = (char*)d_ws;

    // workspace map:
    //   [0,        8,388,608)  A0 f16 [256][16384]   (reused by X2 after gemm1)
    //   [8388608, 13,107,200)  X1 f16 [256][9216]
    //   [13107200,22,544,384)  X3 f32 [256][9216]
    //   [22544384,22,609,920)  XA f32 [256][64]
    //   [22609920, ...)        P  f32 [S][256][9216]
    f16*   A0 = (f16*)(ws + 0);
    f16*   X1 = (f16*)(ws + 8388608);
    f16*   X2 = (f16*)(ws + 0);            // reuses dead A0
    float* X3 = (float*)(ws + 13107200);
    float* XA = (float*)(ws + 22544384);
    float* P  = (float*)(ws + 22609920);

    const size_t pbytes = 9437184ull;      // one splitK plane
    int yshift = (ws_size >= 22609920ull + 4 * pbytes) ? 2 : 1;
    const int S = 1 << yshift;             // S=4 (ws proven >=98 MB by r5 occupancy)

    cvt_kernel<<<2048, 256, 0, stream>>>(s, A0, 256 * 16384);

    const int nblk = (2 * 72) << yshift;   // 576 @ S=4; y = bid & (S-1)
    gemm_kernel<<<nblk, 256, 0, stream>>>(A0, 16384, 16384 / S, yshift, W1, P);
    reduce_kernel<<<1152, 256, 0, stream>>>(P, S, b1, X1, nullptr);
    gemm_kernel<<<nblk, 256, 0, stream>>>(X1, DH, DH / S, yshift, W2, P);
    reduce_kernel<<<1152, 256, 0, stream>>>(P, S, b2, X2, nullptr);
    gemm_kernel<<<nblk, 256, 0, stream>>>(X2, DH, DH / S, yshift, W3, P);
    reduce_kernel<<<1152, 256, 0, stream>>>(P, S, b3, nullptr, X3);

    action_kernel<<<256, 256, 0, stream>>>(X3, Wa, ba, XA);
    select_kernel<<<256, 256, 0, stream>>>(X3, Ws, bs, mask, u, XA, out);
}

// Round 16
// 561.233 us; speedup vs baseline: 1.3958x; 1.1694x over previous
//
#include <hip/hip_runtime.h>
#include <hip/hip_fp16.h>

// ---------------------------------------------------------------------------
// MLPForwardPolicy — r11 champion GEMM (S=8, BM/BN=128, all-DMA, vmcnt(6))
// + f16 split-K partials: P traffic halves (75->37.5 MB per layer each way).
// Precision: partial sums (sigma~0.2) round at ~1e-4, x sqrt(8) ~ 3e-4 on z —
// same order as validated f16-input noise; double-softmax damps to ~1e-6
// score shift. Reduce rewritten for f16x8 loads, single grid-stride pass.
// Ranking: r11=592 r7=606 r10/r15=656 r3=663 r6=669 r8=686 r9=694 r12=783.
// ---------------------------------------------------------------------------

typedef _Float16 f16;
typedef _Float16 f16x4 __attribute__((ext_vector_type(4)));
typedef _Float16 f16x8 __attribute__((ext_vector_type(8)));
typedef float f32x4 __attribute__((ext_vector_type(4)));

#define DH 9216
#define SPLIT 8960

__device__ __forceinline__ void gload16(const void* g, void* l) {
    __builtin_amdgcn_global_load_lds(
        (const __attribute__((address_space(1))) void*)g,
        (__attribute__((address_space(3))) void*)l, 16, 0, 0);
}

// ---------------- f32 -> f16 ----------------
__global__ void cvt_kernel(const float* __restrict__ in, f16* __restrict__ out, int n) {
    for (int i = (blockIdx.x * blockDim.x + threadIdx.x) * 4; i < n;
         i += gridDim.x * blockDim.x * 4) {
        float4 v = *(const float4*)(in + i);
        f16x4 h = {(_Float16)v.x, (_Float16)v.y, (_Float16)v.z, (_Float16)v.w};
        *(f16x4*)(out + i) = h;
    }
}

// ---------------- streaming GEMM: P[y] = A[128-row][Kh] @ W[Kh, 128-col] ----
// linear grid (2*72)<<yshift blocks of 256 threads; y = bid & (S-1)
// rem = bid >> yshift: m0 = (rem&1)*128, n0 = (rem>>1)*128
// 4 waves 2x2: wave(wm,wn) owns rows m0+wm*64..+64 x cols n0+wn*64..+64
__global__ __launch_bounds__(256, 3) void gemm_kernel(
    const f16* __restrict__ A, int K, int Kh, int yshift,
    const float* __restrict__ W,
    f16* __restrict__ P)   // [S][256][9216] f16 partials
{
    __shared__ __align__(16) char lds[2][24576];
    const int bid  = blockIdx.x;
    const int y    = bid & ((1 << yshift) - 1);
    const int rem  = bid >> yshift;
    const int m0   = (rem & 1) << 7;
    const int n0   = (rem >> 1) << 7;
    const int tid  = threadIdx.x;
    const int lane = tid & 63;
    const int wid  = tid >> 6;
    const int wm   = wid >> 1, wn = wid & 1;
    const int kbase = y * Kh;
    const int ns   = Kh >> 5;                     // BK = 32

    f32x4 acc[4][4] = {};

    // ---- hoisted DMA source pointers (advance by one stage per issue) ----
    // W: granule g = tid + r*256 (1024 total): k = g>>5, p = g&31,
    //    src col-group cg = p ^ ((5*(k>>3)) & 31)
    const float* wsrc0;
    const float* wsrc1;
    const float* wsrc2;
    const float* wsrc3;
    {
        int g0 = tid,      k0 = g0 >> 5, c0 = (g0 & 31) ^ ((5 * (k0 >> 3)) & 31);
        int g1 = tid + 256, k1 = g1 >> 5, c1 = (g1 & 31) ^ ((5 * (k1 >> 3)) & 31);
        int g2 = tid + 512, k2 = g2 >> 5, c2 = (g2 & 31) ^ ((5 * (k2 >> 3)) & 31);
        int g3 = tid + 768, k3 = g3 >> 5, c3 = (g3 & 31) ^ ((5 * (k3 >> 3)) & 31);
        wsrc0 = W + (size_t)(kbase + k0) * DH + n0 + (c0 << 2);
        wsrc1 = W + (size_t)(kbase + k1) * DH + n0 + (c1 << 2);
        wsrc2 = W + (size_t)(kbase + k2) * DH + n0 + (c2 << 2);
        wsrc3 = W + (size_t)(kbase + k3) * DH + n0 + (c3 << 2);
    }
    // A: granule h = tid + r*256 (512 total): wmA = h>>8, ri = (h>>6)&3,
    //    q = (h>>4)&3, lc = h&15 -> A[m0 + wmA*64 + ri*16 + lc][kt + q*8..+8]
    const f16* asrc0;
    const f16* asrc1;
    {
        int h0 = tid, h1 = tid + 256;
        int r0 = m0 + ((h0 >> 8) << 6) + (((h0 >> 6) & 3) << 4) + (h0 & 15);
        int r1 = m0 + ((h1 >> 8) << 6) + (((h1 >> 6) & 3) << 4) + (h1 & 15);
        asrc0 = A + (size_t)r0 * K + kbase + (((h0 >> 4) & 3) << 3);
        asrc1 = A + (size_t)r1 * K + kbase + (((h1 >> 4) & 3) << 3);
    }

    auto issue = [&](int slot) {      // 6 DMA instr/thread; advance ptrs 1 stage
        char* dst = &lds[slot][0];
        gload16(wsrc0, dst + (size_t)tid * 16);          wsrc0 += 32 * DH;
        gload16(wsrc1, dst + (size_t)(tid + 256) * 16);  wsrc1 += 32 * DH;
        gload16(wsrc2, dst + (size_t)(tid + 512) * 16);  wsrc2 += 32 * DH;
        gload16(wsrc3, dst + (size_t)(tid + 768) * 16);  wsrc3 += 32 * DH;
        gload16(asrc0, dst + 16384 + (size_t)tid * 16);         asrc0 += 32;
        gload16(asrc1, dst + 16384 + (size_t)(tid + 256) * 16); asrc1 += 32;
    };

    const int q  = lane >> 4;
    const int lc = lane & 15;
    auto step = [&](int slot) {
        const float* wl = (const float*)&lds[slot][0];
        const f16*   al = (const f16*)&lds[slot][16384];
        f16x8 af[4], bf[4];
#pragma unroll
        for (int ri = 0; ri < 4; ++ri)      // lane-linear b128: conflict-free
            af[ri] = *(const f16x8*)(al + (((wm << 8) + (ri << 6) + lane) << 3));
        const int wbase = (q << 10) + (lc & 3);           // k = q*8 -> q*8*128
#pragma unroll
        for (int ni = 0; ni < 4; ++ni) {
            int p = ((wn << 4) + (ni << 2) + (lc >> 2)) ^ (5 * q);
            int fi = wbase + ((p & 31) << 2);
            f16x8 b;
#pragma unroll
            for (int j = 0; j < 8; ++j)
                b[j] = (_Float16)wl[fi + (j << 7)];
            bf[ni] = b;
        }
#pragma unroll
        for (int ri = 0; ri < 4; ++ri)
#pragma unroll
            for (int ni = 0; ni < 4; ++ni)
                acc[ri][ni] = __builtin_amdgcn_mfma_f32_16x16x32_f16(
                    af[ri], bf[ni], acc[ri][ni], 0, 0, 0);
    };

    issue(0);
    issue(1);
    __builtin_amdgcn_sched_barrier(0);

    for (int t = 0; t < ns; ++t) {
        if (t + 1 < ns) asm volatile("s_waitcnt vmcnt(6)" ::: "memory");
        else            asm volatile("s_waitcnt vmcnt(0)" ::: "memory");
        __builtin_amdgcn_sched_barrier(0);
        __builtin_amdgcn_s_barrier();
        __builtin_amdgcn_sched_barrier(0);
        step(t & 1);
        __builtin_amdgcn_sched_barrier(0);
        asm volatile("s_waitcnt lgkmcnt(0)" ::: "memory");
        __builtin_amdgcn_sched_barrier(0);
        __builtin_amdgcn_s_barrier();
        __builtin_amdgcn_sched_barrier(0);
        if (t + 2 < ns) {
            issue(t & 1);
            __builtin_amdgcn_sched_barrier(0);
        }
    }

    // epilogue: D layout col=lane&15, row=(lane>>4)*4+reg  [m89-verified]
    f16* Pb = P + (size_t)y * (256 * DH);
#pragma unroll
    for (int ri = 0; ri < 4; ++ri) {
        int row = m0 + wm * 64 + ri * 16 + (q << 2);
#pragma unroll
        for (int ni = 0; ni < 4; ++ni) {
            int col = n0 + wn * 64 + ni * 16 + lc;
#pragma unroll
            for (int rg = 0; rg < 4; ++rg)
                Pb[(size_t)(row + rg) * DH + col] = (_Float16)acc[ri][ni][rg];
        }
    }
}

// ---------------- splitK reduce (f16 partials) + bias + relu ----------------
// exactly one pass: 1152 blocks x 256 thr x 8 f16 = 2.36M elements
__global__ __launch_bounds__(256) void reduce_kernel(
    const f16* __restrict__ P, int S,
    const float* __restrict__ bias,
    f16* __restrict__ oh, float* __restrict__ out32) {
    const size_t n = 256 * DH;
    const size_t i = ((size_t)blockIdx.x * 256 + threadIdx.x) * 8;
    if (i >= n) return;
    float r[8];
    {
        float4 b0 = *(const float4*)(bias + (i % DH));
        float4 b1 = *(const float4*)(bias + (i % DH) + 4);
        r[0] = b0.x; r[1] = b0.y; r[2] = b0.z; r[3] = b0.w;
        r[4] = b1.x; r[5] = b1.y; r[6] = b1.z; r[7] = b1.w;
    }
    for (int j = 0; j < S; ++j) {
        f16x8 v = *(const f16x8*)(P + (size_t)j * n + i);
#pragma unroll
        for (int e = 0; e < 8; ++e) r[e] += (float)v[e];
    }
#pragma unroll
    for (int e = 0; e < 8; ++e) r[e] = fmaxf(r[e], 0.f);
    if (oh) {
        f16x8 h;
#pragma unroll
        for (int e = 0; e < 8; ++e) h[e] = (_Float16)r[e];
        *(f16x8*)(oh + i) = h;
    }
    if (out32) {
        float4 o0 = {r[0], r[1], r[2], r[3]};
        float4 o1 = {r[4], r[5], r[6], r[7]};
        *(float4*)(out32 + i) = o0;
        *(float4*)(out32 + i + 4) = o1;
    }
}

// ---------------- action head: softmax(X3[:, :8960] @ Wa + ba) --------------
__global__ __launch_bounds__(256) void action_kernel(
    const float* __restrict__ X3, const float* __restrict__ Wa,
    const float* __restrict__ ba, float* __restrict__ xact) {
    __shared__ float xs[SPLIT];
    __shared__ float red[256];
    const int row = blockIdx.x, t = threadIdx.x;
    const float* xr = X3 + (size_t)row * DH;
    for (int k = t * 4; k < SPLIT; k += 1024)
        *(float4*)&xs[k] = *(const float4*)(xr + k);
    __syncthreads();
    const int col = t & 63, kqq = t >> 6;
    float acc = 0.f;
    for (int k = kqq * 2240; k < (kqq + 1) * 2240; ++k)
        acc += xs[k] * Wa[(size_t)k * 64 + col];
    red[t] = acc;
    __syncthreads();
    if (t < 64) {
        float z = red[t] + red[t + 64] + red[t + 128] + red[t + 192] + ba[t];
        float mx = z;
        for (int off = 32; off; off >>= 1) mx = fmaxf(mx, __shfl_xor(mx, off));
        float e = expf(z - mx);
        float s = e;
        for (int off = 32; off; off >>= 1) s += __shfl_xor(s, off);
        xact[row * 64 + t] = e / s;
    }
}

// ---------------- selection head + final outputs ---------------------------
__global__ __launch_bounds__(256) void select_kernel(
    const float* __restrict__ X3, const float* __restrict__ Ws,
    const float* __restrict__ bs, const void* __restrict__ maskp,
    const float* __restrict__ u, const float* __restrict__ xact,
    float* __restrict__ out) {
    __shared__ float xs[256];
    __shared__ float psh[256];
    __shared__ float rr[4];
    __shared__ float bestv[4];
    __shared__ int besti[4];
    __shared__ int sIdx;
    __shared__ int smode;
    const int row = blockIdx.x, t = threadIdx.x;
    const int lane = t & 63, wid = t >> 6;

    // mask dtype detection: int32 {0,1} / bytes {0,1} / float {0.f,1.f}
    if (t < 64) {
        unsigned v = ((const unsigned*)maskp)[t];
        int okInt  = __all(v <= 1u);
        int okByte = __all((v & 0xFEFEFEFEu) == 0u);
        if (t == 0) smode = okInt ? 0 : (okByte ? 1 : 2);
    }
    xs[t] = X3[(size_t)row * DH + SPLIT + t];
    __syncthreads();

    bool mk;
    if (smode == 0)       mk = ((const int*)maskp)[row * 256 + t] != 0;
    else if (smode == 1)  mk = ((const unsigned char*)maskp)[row * 256 + t] != 0;
    else                  mk = ((const float*)maskp)[row * 256 + t] != 0.0f;

    float z = bs[t];
    for (int k = 0; k < 256; ++k)
        z += xs[k] * Ws[k * 256 + t];

    // softmax #1
    float v = z;
    for (int off = 32; off; off >>= 1) v = fmaxf(v, __shfl_xor(v, off));
    if (lane == 0) rr[wid] = v;
    __syncthreads();
    float m1 = fmaxf(fmaxf(rr[0], rr[1]), fmaxf(rr[2], rr[3]));
    __syncthreads();
    float e1 = expf(z - m1);
    v = e1;
    for (int off = 32; off; off >>= 1) v += __shfl_xor(v, off);
    if (lane == 0) rr[wid] = v;
    __syncthreads();
    float s1 = rr[0] + rr[1] + rr[2] + rr[3];
    __syncthreads();
    float p1 = e1 / s1;

    // mask, softmax #2
    float q = mk ? -1e9f : p1;
    v = q;
    for (int off = 32; off; off >>= 1) v = fmaxf(v, __shfl_xor(v, off));
    if (lane == 0) rr[wid] = v;
    __syncthreads();
    float m2 = fmaxf(fmaxf(rr[0], rr[1]), fmaxf(rr[2], rr[3]));
    __syncthreads();
    float e2 = expf(q - m2);
    v = e2;
    for (int off = 32; off; off >>= 1) v += __shfl_xor(v, off);
    if (lane == 0) rr[wid] = v;
    __syncthreads();
    float s2 = rr[0] + rr[1] + rr[2] + rr[3];
    float p2 = e2 / s2;
    psh[t] = p2;

    // gumbel scores + first-occurrence argmax
    float g = -logf(-logf(u[row * 256 + t]));
    float sc = mk ? -INFINITY : (logf(p2) + g);
    float bv = sc;
    int bi = t;
    for (int off = 32; off; off >>= 1) {
        float ov = __shfl_xor(bv, off);
        int oi = __shfl_xor(bi, off);
        if (ov > bv || (ov == bv && oi < bi)) { bv = ov; bi = oi; }
    }
    if (lane == 0) { bestv[wid] = bv; besti[wid] = bi; }
    __syncthreads();
    if (t == 0) {
        float fv = bestv[0];
        int fi = besti[0];
        for (int w = 1; w < 4; ++w)
            if (bestv[w] > fv || (bestv[w] == fv && besti[w] < fi)) {
                fv = bestv[w]; fi = besti[w];
            }
        sIdx = fi;
    }
    __syncthreads();
    const int idx = sIdx;
    const float sp = psh[idx];
    if (t < 64) out[row * 64 + t] = xact[row * 64 + t] * sp;
    if (t == 0) {
        out[256 * 64 + row * 2 + 0] = (float)(idx >> 4);
        out[256 * 64 + row * 2 + 1] = (float)(idx & 15);
    }
}

// ---------------------------------------------------------------------------
extern "C" void kernel_launch(void* const* d_in, const int* in_sizes, int n_in,
                              void* d_out, int out_size, void* d_ws, size_t ws_size,
                              hipStream_t stream) {
    const float* s  = (const float*)d_in[0];
    const void*  mask = d_in[1];
    const float* u  = (const float*)d_in[2];
    const float* W1 = (const float*)d_in[3];
    const float* b1 = (const float*)d_in[4];
    const float* W2 = (const float*)d_in[5];
    const float* b2 = (const float*)d_in[6];
    const float* W3 = (const float*)d_in[7];
    const float* b3 = (const float*)d_in[8];
    const float* Wa = (const float*)d_in[9];
    const float* ba = (const float*)d_in[10];
    const float* Ws = (const float*)d_in[11];
    const float* bs = (const float*)d_in[12];
    float* out = (float*)d_out;
    char* ws = (char*)d_ws;

    // workspace map:
    //   [0,        8,388,608)  A0 f16 [256][16384]   (reused by X2 after gemm1)
    //   [8388608, 13,107,200)  X1 f16 [256][9216]
    //   [13107200,22,544,384)  X3 f32 [256][9216]
    //   [22544384,22,609,920)  XA f32 [256][64]
    //   [22609920, ...)        P  f16 [S][256][9216]  (4.72 MB/plane)
    f16*   A0 = (f16*)(ws + 0);
    f16*   X1 = (f16*)(ws + 8388608);
    f16*   X2 = (f16*)(ws + 0);            // reuses dead A0
    float* X3 = (float*)(ws + 13107200);
    float* XA = (float*)(ws + 22544384);
    f16*   P  = (f16*)(ws + 22609920);

    const size_t pbytes = 4718592ull;      // one f16 splitK plane
    int yshift = (ws_size >= 22609920ull + 8 * pbytes) ? 3 : 2;
    const int S = 1 << yshift;

    cvt_kernel<<<2048, 256, 0, stream>>>(s, A0, 256 * 16384);

    const int nblk = (2 * 72) << yshift;   // 1152 @ S=8; y = bid & (S-1)
    gemm_kernel<<<nblk, 256, 0, stream>>>(A0, 16384, 16384 / S, yshift, W1, P);
    reduce_kernel<<<1152, 256, 0, stream>>>(P, S, b1, X1, nullptr);
    gemm_kernel<<<nblk, 256, 0, stream>>>(X1, DH, DH / S, yshift, W2, P);
    reduce_kernel<<<1152, 256, 0, stream>>>(P, S, b2, X2, nullptr);
    gemm_kernel<<<nblk, 256, 0, stream>>>(X2, DH, DH / S, yshift, W3, P);
    reduce_kernel<<<1152, 256, 0, stream>>>(P, S, b3, nullptr, X3);

    action_kernel<<<256, 256, 0, stream>>>(X3, Wa, ba, XA);
    select_kernel<<<256, 256, 0, stream>>>(X3, Ws, bs, mask, u, XA, out);
}